// Round 1
// baseline (1055.727 us; speedup 1.0000x reference)
//
#include <hip/hip_runtime.h>
#include <math.h>

#define FD 128      // feature dim
#define CLS 40      // classes
#define BN_EPS 1e-5f

// ---------------------------------------------------------------------------
// CSR build: histogram of dst, exclusive scan, scatter src ids
// ---------------------------------------------------------------------------
__global__ void hist_kernel(const int* __restrict__ dst, int* __restrict__ cnt, int E) {
    int e = blockIdx.x * 256 + threadIdx.x;
    if (e < E) atomicAdd(&cnt[dst[e]], 1);
}

__global__ __launch_bounds__(1024) void scan_kernel(const int* __restrict__ cnt,
                                                    int* __restrict__ offs,
                                                    int* __restrict__ cursor, int Nn) {
    __shared__ int warp_sums[16];
    __shared__ int run_s;
    const int t = threadIdx.x;
    const int lane = t & 63, wid = t >> 6;
    if (t == 0) run_s = 0;
    __syncthreads();
    for (int base = 0; base < Nn; base += 1024) {
        int i = base + t;
        int v = (i < Nn) ? cnt[i] : 0;
        int x = v;
        #pragma unroll
        for (int o = 1; o < 64; o <<= 1) {
            int y = __shfl_up(x, o);
            if (lane >= o) x += y;
        }
        if (lane == 63) warp_sums[wid] = x;
        __syncthreads();
        if (t == 0) {
            int acc = run_s;
            #pragma unroll
            for (int w = 0; w < 16; ++w) { int tmp = warp_sums[w]; warp_sums[w] = acc; acc += tmp; }
            run_s = acc;
        }
        __syncthreads();
        if (i < Nn) {
            int excl = warp_sums[wid] + x - v;
            offs[i] = excl;
            cursor[i] = excl;
        }
        __syncthreads();
    }
    if (t == 0) offs[Nn] = run_s;
}

__global__ void scatter_kernel(const int* __restrict__ src, const int* __restrict__ dst,
                               int* __restrict__ cursor, int* __restrict__ col, int E) {
    int e = blockIdx.x * 256 + threadIdx.x;
    if (e < E) {
        int p = atomicAdd(&cursor[dst[e]], 1);
        col[p] = src[e];
    }
}

// ---------------------------------------------------------------------------
// Per-node attention gate: gate[n] = dot(h[n], Wg) + bg   (one wave per node)
// ---------------------------------------------------------------------------
__global__ __launch_bounds__(256) void gate_kernel(const float* __restrict__ h,
                                                   const float* __restrict__ Wg,
                                                   const float* __restrict__ bg,
                                                   float* __restrict__ gate, int Nn) {
    int gt = blockIdx.x * 256 + threadIdx.x;
    int n = gt >> 6, lane = gt & 63;
    if (n >= Nn) return;
    float s = h[n * FD + lane] * Wg[lane] + h[n * FD + lane + 64] * Wg[lane + 64];
    #pragma unroll
    for (int o = 32; o; o >>= 1) s += __shfl_xor(s, o);
    if (lane == 0) gate[n] = s + bg[0];
}

// ---------------------------------------------------------------------------
// Generic M x 128 @ 128 x 128 fp32 GEMM with fused epilogue.
// mode 0: +bias          mode 1: +bias, BN(eval), hardswish      mode 2: +bias, hardswish
// 512 threads, BM=128, BN=128, BK=64 (two chunks), per-thread tile 8x4.
// ---------------------------------------------------------------------------
__device__ __forceinline__ float hswish(float x) {
    return x * fminf(fmaxf(x + 3.0f, 0.0f), 6.0f) * (1.0f / 6.0f);
}

__global__ __launch_bounds__(512) void gemm128_kernel(
    const float* __restrict__ A, const float* __restrict__ B,
    const float* __restrict__ bias,
    const float* __restrict__ bng, const float* __restrict__ bnb,
    const float* __restrict__ bnm, const float* __restrict__ bnv,
    float* __restrict__ out, int M, int mode) {
    __shared__ float As[128 * 64];
    __shared__ float Bs[64 * 128];
    const int t = threadIdx.x;
    const int m0 = blockIdx.x * 128;
    const int tx = t & 31;       // col group: cols c0..c0+3
    const int ty = t >> 5;       // row group: rows r0..r0+7
    const int r0 = ty * 8;
    float acc[8][4] = {};

    for (int kb = 0; kb < 128; kb += 64) {
        __syncthreads();
        #pragma unroll
        for (int i = 0; i < 4; ++i) {          // A chunk: 128 x 64
            int id = i * 512 + t;
            int row = id >> 4, c4 = id & 15;
            int gr = m0 + row;
            float4 v = make_float4(0.f, 0.f, 0.f, 0.f);
            if (gr < M) v = ((const float4*)A)[gr * 32 + (kb >> 2) + c4];
            ((float4*)As)[row * 16 + c4] = v;
        }
        #pragma unroll
        for (int i = 0; i < 4; ++i) {          // B chunk: 64 x 128
            int id = i * 512 + t;
            int row = id >> 5, c4 = id & 31;
            ((float4*)Bs)[row * 32 + c4] = ((const float4*)B)[(kb + row) * 32 + c4];
        }
        __syncthreads();
        for (int k = 0; k < 64; k += 4) {
            float4 b0 = ((float4*)Bs)[(k + 0) * 32 + tx];
            float4 b1 = ((float4*)Bs)[(k + 1) * 32 + tx];
            float4 b2 = ((float4*)Bs)[(k + 2) * 32 + tx];
            float4 b3 = ((float4*)Bs)[(k + 3) * 32 + tx];
            #pragma unroll
            for (int r = 0; r < 8; ++r) {
                float4 a = ((float4*)As)[(r0 + r) * 16 + (k >> 2)];
                acc[r][0] += a.x * b0.x + a.y * b1.x + a.z * b2.x + a.w * b3.x;
                acc[r][1] += a.x * b0.y + a.y * b1.y + a.z * b2.y + a.w * b3.y;
                acc[r][2] += a.x * b0.z + a.y * b1.z + a.z * b2.z + a.w * b3.z;
                acc[r][3] += a.x * b0.w + a.y * b1.w + a.z * b2.w + a.w * b3.w;
            }
        }
    }

    float4 bb = ((const float4*)bias)[tx];
    float4 sc = make_float4(0.f, 0.f, 0.f, 0.f), sh = make_float4(0.f, 0.f, 0.f, 0.f);
    if (mode == 1) {
        float4 g = ((const float4*)bng)[tx];
        float4 b = ((const float4*)bnb)[tx];
        float4 m = ((const float4*)bnm)[tx];
        float4 v = ((const float4*)bnv)[tx];
        sc.x = g.x * rsqrtf(v.x + BN_EPS); sh.x = b.x - m.x * sc.x;
        sc.y = g.y * rsqrtf(v.y + BN_EPS); sh.y = b.y - m.y * sc.y;
        sc.z = g.z * rsqrtf(v.z + BN_EPS); sh.z = b.z - m.z * sc.z;
        sc.w = g.w * rsqrtf(v.w + BN_EPS); sh.w = b.w - m.w * sc.w;
    }
    #pragma unroll
    for (int r = 0; r < 8; ++r) {
        int gr = m0 + r0 + r;
        if (gr >= M) continue;
        float4 z;
        z.x = acc[r][0] + bb.x; z.y = acc[r][1] + bb.y;
        z.z = acc[r][2] + bb.z; z.w = acc[r][3] + bb.w;
        if (mode == 1) {
            z.x = z.x * sc.x + sh.x; z.y = z.y * sc.y + sh.y;
            z.z = z.z * sc.z + sh.z; z.w = z.w * sc.w + sh.w;
        }
        if (mode != 0) {
            z.x = hswish(z.x); z.y = hswish(z.y); z.z = hswish(z.z); z.w = hswish(z.w);
        }
        ((float4*)out)[gr * 32 + tx] = z;
    }
}

// ---------------------------------------------------------------------------
// Attention aggregation (one wave per dst node), self loop included.
// agg[n] = (sum_e exp(g[src]-m) * ht[src] + exp(g[n]-m) * ht[n]) / denom
// ---------------------------------------------------------------------------
__global__ __launch_bounds__(256) void agg_kernel(const float* __restrict__ gate,
                                                  const float* __restrict__ ht,
                                                  const int* __restrict__ offs,
                                                  const int* __restrict__ col,
                                                  float* __restrict__ agg, int Nn) {
    int gt = blockIdx.x * 256 + threadIdx.x;
    int n = gt >> 6, lane = gt & 63;
    if (n >= Nn) return;
    int beg = offs[n], end = offs[n + 1];
    float gs = gate[n];
    float m = gs;
    for (int e = beg + lane; e < end; e += 64) m = fmaxf(m, gate[col[e]]);
    #pragma unroll
    for (int o = 32; o; o >>= 1) m = fmaxf(m, __shfl_xor(m, o));
    float s = 0.f;
    for (int e = beg + lane; e < end; e += 64) s += __expf(gate[col[e]] - m);
    #pragma unroll
    for (int o = 32; o; o >>= 1) s += __shfl_xor(s, o);
    float wself = __expf(gs - m);
    float denom = s + wself;
    float a0 = wself * ht[n * FD + lane];
    float a1 = wself * ht[n * FD + lane + 64];
    for (int e = beg; e < end; ++e) {
        int c = col[e];
        float w = __expf(gate[c] - m);
        a0 += w * ht[c * FD + lane];
        a1 += w * ht[c * FD + lane + 64];
    }
    float inv = 1.0f / denom;
    agg[n * FD + lane] = a0 * inv;
    agg[n * FD + lane + 64] = a1 * inv;
}

// ---------------------------------------------------------------------------
// Head: logits = hp @ Wp2 + bp2 ; out = log_softmax(logits)  (one wave/node)
// ---------------------------------------------------------------------------
__global__ __launch_bounds__(256) void head_kernel(const float* __restrict__ hp,
                                                   const float* __restrict__ Wp2,
                                                   const float* __restrict__ bp2,
                                                   float* __restrict__ out, int Nn) {
    __shared__ float w2s[FD * CLS];
    __shared__ float hsh[4][FD];
    const int t = threadIdx.x;
    for (int i = t; i < FD * CLS; i += 256) w2s[i] = Wp2[i];
    const int w = t >> 6, lane = t & 63;
    const int n = blockIdx.x * 4 + w;
    const bool act = n < Nn;
    if (act) {
        hsh[w][lane] = hp[n * FD + lane];
        hsh[w][lane + 64] = hp[n * FD + lane + 64];
    }
    __syncthreads();
    float val = 0.f;
    if (act && lane < CLS) {
        val = bp2[lane];
        for (int k = 0; k < FD; ++k) val += hsh[w][k] * w2s[k * CLS + lane];
    }
    float lg = (act && lane < CLS) ? val : -INFINITY;
    float m = lg;
    #pragma unroll
    for (int o = 32; o; o >>= 1) m = fmaxf(m, __shfl_xor(m, o));
    float ex = (act && lane < CLS) ? __expf(val - m) : 0.f;
    float s = ex;
    #pragma unroll
    for (int o = 32; o; o >>= 1) s += __shfl_xor(s, o);
    if (act && lane < CLS) out[n * CLS + lane] = val - m - __logf(s);
}

// ---------------------------------------------------------------------------
extern "C" void kernel_launch(void* const* d_in, const int* in_sizes, int n_in,
                              void* d_out, int out_size, void* d_ws, size_t ws_size,
                              hipStream_t stream) {
    const float* x   = (const float*)d_in[0];
    const int*   src = (const int*)d_in[1];
    const int*   dst = (const int*)d_in[2];
    const float* Wg  = (const float*)d_in[3];
    const float* bg  = (const float*)d_in[4];
    const float* Wt  = (const float*)d_in[5];
    const float* bt  = (const float*)d_in[6];
    const float* W1  = (const float*)d_in[7];
    const float* b1  = (const float*)d_in[8];
    const float* bng = (const float*)d_in[9];
    const float* bnb = (const float*)d_in[10];
    const float* bnm = (const float*)d_in[11];
    const float* bnv = (const float*)d_in[12];
    const float* W2  = (const float*)d_in[13];
    const float* b2  = (const float*)d_in[14];
    const float* Wp1 = (const float*)d_in[15];
    const float* bp1 = (const float*)d_in[16];
    const float* Wp2 = (const float*)d_in[17];
    const float* bp2 = (const float*)d_in[18];
    float* out = (float*)d_out;

    const int N = in_sizes[0] / FD;
    const int E = in_sizes[1];
    const int L = in_sizes[3] / FD;

    float* h    = (float*)d_ws;
    float* ht   = h   + (size_t)N * FD;
    float* agg  = ht  + (size_t)N * FD;
    float* gate = agg + (size_t)N * FD;
    int* counts = (int*)(gate + N);
    int* offs   = counts + N;
    int* cursor = offs + (N + 1);
    int* col    = cursor + N;

    // --- CSR build (graph is static; rebuilt each call since ws is poisoned)
    hipMemsetAsync(counts, 0, N * sizeof(int), stream);
    hist_kernel<<<(E + 255) / 256, 256, 0, stream>>>(dst, counts, E);
    scan_kernel<<<1, 1024, 0, stream>>>(counts, offs, cursor, N);
    scatter_kernel<<<(E + 255) / 256, 256, 0, stream>>>(src, dst, cursor, col, E);

    hipMemcpyAsync(h, x, (size_t)N * FD * sizeof(float), hipMemcpyDeviceToDevice, stream);

    const int gemm_grid = (N + 127) / 128;
    const int wave_grid = (N + 3) / 4;

    for (int i = 0; i < L; ++i) {
        gate_kernel<<<wave_grid, 256, 0, stream>>>(h, Wg + i * FD, bg + i, gate, N);
        gemm128_kernel<<<gemm_grid, 512, 0, stream>>>(h, Wt + i * FD * FD, bt + i * FD,
            nullptr, nullptr, nullptr, nullptr, ht, N, 0);
        agg_kernel<<<wave_grid, 256, 0, stream>>>(gate, ht, offs, col, agg, N);
        gemm128_kernel<<<gemm_grid, 512, 0, stream>>>(agg, W1 + i * FD * FD, b1 + i * FD,
            bng + i * FD, bnb + i * FD, bnm + i * FD, bnv + i * FD, ht, N, 1);
        gemm128_kernel<<<gemm_grid, 512, 0, stream>>>(ht, W2 + i * FD * FD, b2 + i * FD,
            nullptr, nullptr, nullptr, nullptr, h, N, 2);
    }
    gemm128_kernel<<<gemm_grid, 512, 0, stream>>>(h, Wp1, bp1,
        nullptr, nullptr, nullptr, nullptr, ht, N, 2);
    head_kernel<<<wave_grid, 256, 0, stream>>>(ht, Wp2, bp2, out, N);
}

// Round 2
// 767.739 us; speedup vs baseline: 1.3751x; 1.3751x over previous
//
#include <hip/hip_runtime.h>
#include <math.h>

#define FD 128      // feature dim
#define CLS 40      // classes
#define BN_EPS 1e-5f
#define AS_STRIDE 136   // 128 + 8 bf16 pad: 2-way LDS bank aliasing only (free)

typedef short short8 __attribute__((ext_vector_type(8)));
typedef float floatx4 __attribute__((ext_vector_type(4)));
typedef unsigned short ushort4v __attribute__((ext_vector_type(4)));

__device__ __forceinline__ unsigned short bf16_of(float v) {
    unsigned int u = __float_as_uint(v);
    unsigned int r = u + 0x7FFFu + ((u >> 16) & 1u);   // RNE
    return (unsigned short)(r >> 16);
}
__device__ __forceinline__ float bf16f(unsigned short h) {
    return __uint_as_float(((unsigned int)h) << 16);
}
__device__ __forceinline__ float hswish(float x) {
    return x * fminf(fmaxf(x + 3.0f, 0.0f), 6.0f) * (1.0f / 6.0f);
}

// ---------------------------------------------------------------------------
// CSR build
// ---------------------------------------------------------------------------
__global__ void hist_kernel(const int* __restrict__ dst, int* __restrict__ cnt, int E) {
    int e = blockIdx.x * 256 + threadIdx.x;
    if (e < E) atomicAdd(&cnt[dst[e]], 1);
}

__global__ __launch_bounds__(1024) void scan_kernel(const int* __restrict__ cnt,
                                                    int* __restrict__ offs,
                                                    int* __restrict__ cursor, int Nn) {
    __shared__ int warp_sums[16];
    __shared__ int run_s;
    const int t = threadIdx.x;
    const int lane = t & 63, wid = t >> 6;
    if (t == 0) run_s = 0;
    __syncthreads();
    for (int base = 0; base < Nn; base += 1024) {
        int i = base + t;
        int v = (i < Nn) ? cnt[i] : 0;
        int x = v;
        #pragma unroll
        for (int o = 1; o < 64; o <<= 1) {
            int y = __shfl_up(x, o);
            if (lane >= o) x += y;
        }
        if (lane == 63) warp_sums[wid] = x;
        __syncthreads();
        if (t == 0) {
            int acc = run_s;
            #pragma unroll
            for (int w = 0; w < 16; ++w) { int tmp = warp_sums[w]; warp_sums[w] = acc; acc += tmp; }
            run_s = acc;
        }
        __syncthreads();
        if (i < Nn) {
            int excl = warp_sums[wid] + x - v;
            offs[i] = excl;
            cursor[i] = excl;
        }
        __syncthreads();
    }
    if (t == 0) offs[Nn] = run_s;
}

__global__ void scatter_kernel(const int* __restrict__ src, const int* __restrict__ dst,
                               int* __restrict__ cursor, int* __restrict__ col, int E) {
    int e = blockIdx.x * 256 + threadIdx.x;
    if (e < E) {
        int p = atomicAdd(&cursor[dst[e]], 1);
        col[p] = src[e];
    }
}

// ---------------------------------------------------------------------------
// Weight prep: split each W[k][n] into bf16 hi/lo, store transposed [n][k].
// Slot m occupies 32768 shorts: hi at +0, lo at +16384 (square) / +6144 (Wp2).
// ---------------------------------------------------------------------------
__global__ void prep_weights(const float* __restrict__ Wt, const float* __restrict__ W1,
                             const float* __restrict__ W2, const float* __restrict__ Wp1,
                             const float* __restrict__ Wp2,
                             unsigned short* __restrict__ wbuf, int L) {
    const int m = blockIdx.y;
    const int id = blockIdx.x * 256 + threadIdx.x;
    const int nsq = 3 * L + 1;
    unsigned short* base = wbuf + (size_t)m * 32768;
    if (m < nsq) {
        const float* src = (m < L) ? Wt + m * 16384
                         : (m < 2 * L) ? W1 + (m - L) * 16384
                         : (m < 3 * L) ? W2 + (m - 2 * L) * 16384
                         : Wp1;
        int n = id >> 7, k = id & 127;
        float v = src[k * 128 + n];
        unsigned short h = bf16_of(v);
        unsigned short l = bf16_of(v - bf16f(h));
        base[n * 128 + k] = h;
        base[16384 + n * 128 + k] = l;
    } else {                      // Wp2: [128][40] -> padded [48][128]
        if (id >= 48 * 128) return;
        int n = id >> 7, k = id & 127;
        float v = (n < CLS) ? Wp2[k * CLS + n] : 0.f;
        unsigned short h = bf16_of(v);
        unsigned short l = bf16_of(v - bf16f(h));
        base[n * 128 + k] = h;
        base[6144 + n * 128 + k] = l;
    }
}

// ---------------------------------------------------------------------------
// Shared GEMM building blocks (128-row block tile, 4 waves x 32 rows, K=128)
// A-frag: A[m=lane&15][k=quad*8+j]   B-frag: B[k=quad*8+j][n=lane&15]
// C/D:    row=quad*4+reg, col=lane&15      (measured layouts, m89/m91/m120)
// ---------------------------------------------------------------------------
__device__ __forceinline__ void stage_A(const float* __restrict__ A, int m0, int M,
                                        unsigned short* As_hi, unsigned short* As_lo, int t) {
    #pragma unroll
    for (int i = 0; i < 16; ++i) {
        int id = i * 256 + t;
        int row = id >> 5, c4 = id & 31;
        float4 v = make_float4(0.f, 0.f, 0.f, 0.f);
        if (m0 + row < M) v = ((const float4*)A)[(size_t)(m0 + row) * 32 + c4];
        unsigned short h0 = bf16_of(v.x), h1 = bf16_of(v.y), h2 = bf16_of(v.z), h3 = bf16_of(v.w);
        ushort4v hh = {h0, h1, h2, h3};
        ushort4v ll = {bf16_of(v.x - bf16f(h0)), bf16_of(v.y - bf16f(h1)),
                       bf16_of(v.z - bf16f(h2)), bf16_of(v.w - bf16f(h3))};
        *(ushort4v*)(&As_hi[row * AS_STRIDE + c4 * 4]) = hh;
        *(ushort4v*)(&As_lo[row * AS_STRIDE + c4 * 4]) = ll;
    }
}

template <int NCT>
__device__ __forceinline__ void mfma_core(const unsigned short* __restrict__ Bh,
                                          const unsigned short* __restrict__ Bl,
                                          const unsigned short* As_hi, const unsigned short* As_lo,
                                          int wr0, int l16, int quad, floatx4 acc[2][NCT]) {
    #pragma unroll
    for (int kc = 0; kc < 4; ++kc) {
        short8 ah[2], al[2];
        #pragma unroll
        for (int rt = 0; rt < 2; ++rt) {
            int off = (wr0 + rt * 16 + l16) * AS_STRIDE + kc * 32 + quad * 8;
            ah[rt] = *(const short8*)(&As_hi[off]);
            al[rt] = *(const short8*)(&As_lo[off]);
        }
        #pragma unroll
        for (int ct = 0; ct < NCT; ++ct) {
            int boff = (ct * 16 + l16) * 128 + kc * 32 + quad * 8;
            short8 bh = *(const short8*)(&Bh[boff]);
            short8 bl = *(const short8*)(&Bl[boff]);
            #pragma unroll
            for (int rt = 0; rt < 2; ++rt) {
                acc[rt][ct] = __builtin_amdgcn_mfma_f32_16x16x32_bf16(ah[rt], bh, acc[rt][ct], 0, 0, 0);
                acc[rt][ct] = __builtin_amdgcn_mfma_f32_16x16x32_bf16(ah[rt], bl, acc[rt][ct], 0, 0, 0);
                acc[rt][ct] = __builtin_amdgcn_mfma_f32_16x16x32_bf16(al[rt], bh, acc[rt][ct], 0, 0, 0);
            }
        }
    }
}

// ---------------------------------------------------------------------------
// ht = A @ W + bias   (split-bf16 MFMA, fp32 out)
// ---------------------------------------------------------------------------
__global__ __launch_bounds__(256) void gemm_bias_kernel(
    const float* __restrict__ A, const unsigned short* __restrict__ Bh,
    const unsigned short* __restrict__ Bl, const float* __restrict__ bias,
    float* __restrict__ out, int M) {
    __shared__ unsigned short As_hi[128 * AS_STRIDE];
    __shared__ unsigned short As_lo[128 * AS_STRIDE];
    const int t = threadIdx.x, m0 = blockIdx.x * 128;
    stage_A(A, m0, M, As_hi, As_lo, t);
    __syncthreads();
    const int lane = t & 63, l16 = lane & 15, quad = lane >> 4, wr0 = (t >> 6) * 32;
    floatx4 acc[2][8];
    #pragma unroll
    for (int rt = 0; rt < 2; ++rt)
        #pragma unroll
        for (int ct = 0; ct < 8; ++ct) acc[rt][ct] = (floatx4){0.f, 0.f, 0.f, 0.f};
    mfma_core<8>(Bh, Bl, As_hi, As_lo, wr0, l16, quad, acc);
    #pragma unroll
    for (int rt = 0; rt < 2; ++rt)
        #pragma unroll
        for (int ct = 0; ct < 8; ++ct) {
            int c = ct * 16 + l16;
            float b = bias[c];
            #pragma unroll
            for (int reg = 0; reg < 4; ++reg) {
                int row = m0 + wr0 + rt * 16 + quad * 4 + reg;
                if (row < M) out[(size_t)row * 128 + c] = acc[rt][ct][reg] + b;
            }
        }
}

// ---------------------------------------------------------------------------
// h = hswish( hswish(BN(A@W1+b1)) @ W2 + b2 )  — fused double GEMM.
// z tile round-trips through As LDS in bf16 hi/lo; rows are wave-private so
// no barrier needed between GEMM1 epilogue and GEMM2.
// ---------------------------------------------------------------------------
__global__ __launch_bounds__(256) void layer_kernel(
    const float* __restrict__ A,
    const unsigned short* __restrict__ B1h, const unsigned short* __restrict__ B1l,
    const float* __restrict__ b1,
    const float* __restrict__ bng, const float* __restrict__ bnb,
    const float* __restrict__ bnm, const float* __restrict__ bnv,
    const unsigned short* __restrict__ B2h, const unsigned short* __restrict__ B2l,
    const float* __restrict__ b2, float* __restrict__ out, int M) {
    __shared__ unsigned short As_hi[128 * AS_STRIDE];
    __shared__ unsigned short As_lo[128 * AS_STRIDE];
    const int t = threadIdx.x, m0 = blockIdx.x * 128;
    stage_A(A, m0, M, As_hi, As_lo, t);
    __syncthreads();
    const int lane = t & 63, l16 = lane & 15, quad = lane >> 4, wr0 = (t >> 6) * 32;
    floatx4 acc[2][8];
    #pragma unroll
    for (int rt = 0; rt < 2; ++rt)
        #pragma unroll
        for (int ct = 0; ct < 8; ++ct) acc[rt][ct] = (floatx4){0.f, 0.f, 0.f, 0.f};
    mfma_core<8>(B1h, B1l, As_hi, As_lo, wr0, l16, quad, acc);
    // epilogue 1: z = hswish(BN(acc+b1)) -> bf16 hi/lo back into As (own rows)
    #pragma unroll
    for (int rt = 0; rt < 2; ++rt)
        #pragma unroll
        for (int ct = 0; ct < 8; ++ct) {
            int c = ct * 16 + l16;
            float sc = bng[c] * rsqrtf(bnv[c] + BN_EPS);
            float sh = bnb[c] - bnm[c] * sc;
            float bb = b1[c];
            #pragma unroll
            for (int reg = 0; reg < 4; ++reg) {
                int r = wr0 + rt * 16 + quad * 4 + reg;   // local row
                float z = hswish((acc[rt][ct][reg] + bb) * sc + sh);
                unsigned short h = bf16_of(z);
                As_hi[r * AS_STRIDE + c] = h;
                As_lo[r * AS_STRIDE + c] = bf16_of(z - bf16f(h));
            }
        }
    #pragma unroll
    for (int rt = 0; rt < 2; ++rt)
        #pragma unroll
        for (int ct = 0; ct < 8; ++ct) acc[rt][ct] = (floatx4){0.f, 0.f, 0.f, 0.f};
    mfma_core<8>(B2h, B2l, As_hi, As_lo, wr0, l16, quad, acc);
    #pragma unroll
    for (int rt = 0; rt < 2; ++rt)
        #pragma unroll
        for (int ct = 0; ct < 8; ++ct) {
            int c = ct * 16 + l16;
            float b = b2[c];
            #pragma unroll
            for (int reg = 0; reg < 4; ++reg) {
                int row = m0 + wr0 + rt * 16 + quad * 4 + reg;
                if (row < M) out[(size_t)row * 128 + c] = hswish(acc[rt][ct][reg] + b);
            }
        }
}

// ---------------------------------------------------------------------------
// out = log_softmax( hswish(A@Wp1+bp1) @ Wp2 + bp2 ) — fused head.
// ---------------------------------------------------------------------------
__global__ __launch_bounds__(256) void head_kernel(
    const float* __restrict__ A,
    const unsigned short* __restrict__ B1h, const unsigned short* __restrict__ B1l,
    const float* __restrict__ bp1,
    const unsigned short* __restrict__ B2h, const unsigned short* __restrict__ B2l,
    const float* __restrict__ bp2, float* __restrict__ out, int M) {
    __shared__ unsigned short As_hi[128 * AS_STRIDE];
    __shared__ unsigned short As_lo[128 * AS_STRIDE];
    const int t = threadIdx.x, m0 = blockIdx.x * 128;
    stage_A(A, m0, M, As_hi, As_lo, t);
    __syncthreads();
    const int lane = t & 63, l16 = lane & 15, quad = lane >> 4, wr0 = (t >> 6) * 32;
    floatx4 acc[2][8];
    #pragma unroll
    for (int rt = 0; rt < 2; ++rt)
        #pragma unroll
        for (int ct = 0; ct < 8; ++ct) acc[rt][ct] = (floatx4){0.f, 0.f, 0.f, 0.f};
    mfma_core<8>(B1h, B1l, As_hi, As_lo, wr0, l16, quad, acc);
    #pragma unroll
    for (int rt = 0; rt < 2; ++rt)
        #pragma unroll
        for (int ct = 0; ct < 8; ++ct) {
            int c = ct * 16 + l16;
            float bb = bp1[c];
            #pragma unroll
            for (int reg = 0; reg < 4; ++reg) {
                int r = wr0 + rt * 16 + quad * 4 + reg;
                float z = hswish(acc[rt][ct][reg] + bb);
                unsigned short h = bf16_of(z);
                As_hi[r * AS_STRIDE + c] = h;
                As_lo[r * AS_STRIDE + c] = bf16_of(z - bf16f(h));
            }
        }
    floatx4 acc2[2][3];
    #pragma unroll
    for (int rt = 0; rt < 2; ++rt)
        #pragma unroll
        for (int ct = 0; ct < 3; ++ct) acc2[rt][ct] = (floatx4){0.f, 0.f, 0.f, 0.f};
    mfma_core<3>(B2h, B2l, As_hi, As_lo, wr0, l16, quad, acc2);
    // log_softmax over 40 cols; row lives in one quad (16 lanes x 3 regs = 48 cols)
    #pragma unroll
    for (int rt = 0; rt < 2; ++rt)
        #pragma unroll
        for (int reg = 0; reg < 4; ++reg) {
            float v[3];
            #pragma unroll
            for (int ct = 0; ct < 3; ++ct) {
                int c = ct * 16 + l16;
                v[ct] = (c < CLS) ? acc2[rt][ct][reg] + bp2[c] : -INFINITY;
            }
            float mx = fmaxf(fmaxf(v[0], v[1]), v[2]);
            #pragma unroll
            for (int o = 1; o < 16; o <<= 1) mx = fmaxf(mx, __shfl_xor(mx, o));
            float s = 0.f;
            #pragma unroll
            for (int ct = 0; ct < 3; ++ct) s += (v[ct] > -INFINITY) ? __expf(v[ct] - mx) : 0.f;
            #pragma unroll
            for (int o = 1; o < 16; o <<= 1) s += __shfl_xor(s, o);
            float lse = mx + __logf(s);
            int row = m0 + wr0 + rt * 16 + quad * 4 + reg;
            if (row < M) {
                #pragma unroll
                for (int ct = 0; ct < 3; ++ct) {
                    int c = ct * 16 + l16;
                    if (c < CLS) out[(size_t)row * CLS + c] = v[ct] - lse;
                }
            }
        }
}

// ---------------------------------------------------------------------------
// gate[n] = dot(h[n], Wg) + bg   (one wave per node)
// ---------------------------------------------------------------------------
__global__ __launch_bounds__(256) void gate_kernel(const float* __restrict__ h,
                                                   const float* __restrict__ Wg,
                                                   const float* __restrict__ bg,
                                                   float* __restrict__ gate, int Nn) {
    int gt = blockIdx.x * 256 + threadIdx.x;
    int n = gt >> 6, lane = gt & 63;
    if (n >= Nn) return;
    float s = h[(size_t)n * FD + lane] * Wg[lane] + h[(size_t)n * FD + lane + 64] * Wg[lane + 64];
    #pragma unroll
    for (int o = 32; o; o >>= 1) s += __shfl_xor(s, o);
    if (lane == 0) gate[n] = s + bg[0];
}

// ---------------------------------------------------------------------------
// Attention aggregation, one wave per dst node, edge loop unrolled x4 for MLP
// ---------------------------------------------------------------------------
__global__ __launch_bounds__(256) void agg_kernel(const float* __restrict__ gate,
                                                  const float* __restrict__ ht,
                                                  const int* __restrict__ offs,
                                                  const int* __restrict__ col,
                                                  float* __restrict__ agg, int Nn) {
    int gt = blockIdx.x * 256 + threadIdx.x;
    int n = gt >> 6, lane = gt & 63;
    if (n >= Nn) return;
    int beg = offs[n], end = offs[n + 1];
    float gs = gate[n];
    float m = gs;
    for (int e = beg + lane; e < end; e += 64) m = fmaxf(m, gate[col[e]]);
    #pragma unroll
    for (int o = 32; o; o >>= 1) m = fmaxf(m, __shfl_xor(m, o));
    float wself = __expf(gs - m);
    float denom = wself;
    float a0 = wself * ht[(size_t)n * FD + lane];
    float a1 = wself * ht[(size_t)n * FD + lane + 64];
    int e = beg;
    for (; e + 4 <= end; e += 4) {
        int c0 = col[e], c1 = col[e + 1], c2 = col[e + 2], c3 = col[e + 3];
        float g0 = gate[c0], g1 = gate[c1], g2 = gate[c2], g3 = gate[c3];
        const float* p0 = &ht[(size_t)c0 * FD + lane];
        const float* p1 = &ht[(size_t)c1 * FD + lane];
        const float* p2 = &ht[(size_t)c2 * FD + lane];
        const float* p3 = &ht[(size_t)c3 * FD + lane];
        float h00 = p0[0], h01 = p0[64];
        float h10 = p1[0], h11 = p1[64];
        float h20 = p2[0], h21 = p2[64];
        float h30 = p3[0], h31 = p3[64];
        float w0 = __expf(g0 - m), w1 = __expf(g1 - m);
        float w2 = __expf(g2 - m), w3 = __expf(g3 - m);
        denom += (w0 + w1) + (w2 + w3);
        a0 += w0 * h00 + w1 * h10 + w2 * h20 + w3 * h30;
        a1 += w0 * h01 + w1 * h11 + w2 * h21 + w3 * h31;
    }
    for (; e < end; ++e) {
        int c = col[e];
        float w = __expf(gate[c] - m);
        denom += w;
        a0 += w * ht[(size_t)c * FD + lane];
        a1 += w * ht[(size_t)c * FD + lane + 64];
    }
    float inv = 1.0f / denom;
    agg[(size_t)n * FD + lane] = a0 * inv;
    agg[(size_t)n * FD + lane + 64] = a1 * inv;
}

// ---------------------------------------------------------------------------
extern "C" void kernel_launch(void* const* d_in, const int* in_sizes, int n_in,
                              void* d_out, int out_size, void* d_ws, size_t ws_size,
                              hipStream_t stream) {
    const float* x   = (const float*)d_in[0];
    const int*   src = (const int*)d_in[1];
    const int*   dst = (const int*)d_in[2];
    const float* Wg  = (const float*)d_in[3];
    const float* bg  = (const float*)d_in[4];
    const float* Wt  = (const float*)d_in[5];
    const float* bt  = (const float*)d_in[6];
    const float* W1  = (const float*)d_in[7];
    const float* b1  = (const float*)d_in[8];
    const float* bng = (const float*)d_in[9];
    const float* bnb = (const float*)d_in[10];
    const float* bnm = (const float*)d_in[11];
    const float* bnv = (const float*)d_in[12];
    const float* W2  = (const float*)d_in[13];
    const float* b2  = (const float*)d_in[14];
    const float* Wp1 = (const float*)d_in[15];
    const float* bp1 = (const float*)d_in[16];
    const float* Wp2 = (const float*)d_in[17];
    const float* bp2 = (const float*)d_in[18];
    float* out = (float*)d_out;

    const int N = in_sizes[0] / FD;
    const int E = in_sizes[1];
    const int L = in_sizes[3] / FD;

    float* h    = (float*)d_ws;
    float* ht   = h   + (size_t)N * FD;
    float* agg  = ht  + (size_t)N * FD;
    float* gate = agg + (size_t)N * FD;
    unsigned short* wbuf = (unsigned short*)(gate + N);   // 16B-aligned (N*4 % 16 == 0)
    int* counts = (int*)(wbuf + (size_t)(3 * L + 2) * 32768);
    int* offs   = counts + N;
    int* cursor = offs + (N + 1);
    int* col    = cursor + N;

    // --- CSR build + weight split (graph/weights static, ws re-poisoned each call)
    hipMemsetAsync(counts, 0, N * sizeof(int), stream);
    hist_kernel<<<(E + 255) / 256, 256, 0, stream>>>(dst, counts, E);
    prep_weights<<<dim3(64, 3 * L + 2), 256, 0, stream>>>(Wt, W1, W2, Wp1, Wp2, wbuf, L);
    scan_kernel<<<1, 1024, 0, stream>>>(counts, offs, cursor, N);
    scatter_kernel<<<(E + 255) / 256, 256, 0, stream>>>(src, dst, cursor, col, E);

    const int gemm_grid = (N + 127) / 128;
    const int wave_grid = (N + 3) / 4;

    for (int i = 0; i < L; ++i) {
        const float* hin = (i == 0) ? x : h;
        unsigned short* wt = wbuf + (size_t)i * 32768;
        unsigned short* w1 = wbuf + (size_t)(L + i) * 32768;
        unsigned short* w2 = wbuf + (size_t)(2 * L + i) * 32768;
        gate_kernel<<<wave_grid, 256, 0, stream>>>(hin, Wg + i * FD, bg + i, gate, N);
        gemm_bias_kernel<<<gemm_grid, 256, 0, stream>>>(hin, wt, wt + 16384, bt + i * FD, ht, N);
        agg_kernel<<<wave_grid, 256, 0, stream>>>(gate, ht, offs, col, agg, N);
        layer_kernel<<<gemm_grid, 256, 0, stream>>>(agg,
            w1, w1 + 16384, b1 + i * FD,
            bng + i * FD, bnb + i * FD, bnm + i * FD, bnv + i * FD,
            w2, w2 + 16384, b2 + i * FD, h, N);
    }
    unsigned short* wp1 = wbuf + (size_t)(3 * L) * 32768;
    unsigned short* wp2 = wbuf + (size_t)(3 * L + 1) * 32768;
    head_kernel<<<gemm_grid, 256, 0, stream>>>(h, wp1, wp1 + 16384, bp1,
                                               wp2, wp2 + 6144, bp2, out, N);
}